// Round 6
// baseline (284.026 us; speedup 1.0000x reference)
//
#include <hip/hip_runtime.h>

#define LSIZE 24
#define VOL (LSIZE*LSIZE*LSIZE*LSIZE)       // 331776 sites
#define NLINES (LSIZE*LSIZE*LSIZE)          // 13824 lines per direction
#define LPB 8                               // lines per tile (= 1 wave)
#define TPB 64
#define NT 2                                // tiles per block, software-pipelined
#define OCT (NLINES/LPB)                    // 1728 octet-tiles per direction
#define IMG 1728                            // dwords per re/im image (8*24*9)
#define NCHUNK 864                          // float4 chunks per tile image

// (o_re,o_im) = a * b, complex 3x3 matmul (row-major). Output must not alias inputs.
__device__ __forceinline__ void cmul(const float* __restrict__ ar, const float* __restrict__ ai,
                                     const float* __restrict__ br, const float* __restrict__ bi,
                                     float* __restrict__ or_, float* __restrict__ oi_) {
#pragma unroll
  for (int i = 0; i < 3; ++i) {
#pragma unroll
    for (int j = 0; j < 3; ++j) {
      float sr = 0.f, si = 0.f;
#pragma unroll
      for (int m = 0; m < 3; ++m) {
        float x = ar[i*3+m], y = ai[i*3+m];
        float u = br[m*3+j], v = bi[m*3+j];
        sr = fmaf(x, u, sr);
        sr = fmaf(-y, v, sr);
        si = fmaf(x, v, si);
        si = fmaf(y, u, si);
      }
      or_[i*3+j] = sr;
      oi_[i*3+j] = si;
    }
  }
}

__device__ __forceinline__ void cp9(float* dr, float* di, const float* sr, const float* si) {
#pragma unroll
  for (int e = 0; e < 9; ++e) { dr[e] = sr[e]; di[e] = si[e]; }
}

__device__ __forceinline__ void setid(float* r, float* im) {
#pragma unroll
  for (int e = 0; e < 9; ++e) { r[e] = (e == 0 || e == 4 || e == 8) ? 1.f : 0.f; im[e] = 0.f; }
}

__device__ __forceinline__ void shup(float* dr, float* di, const float* sr, const float* si, int delta) {
#pragma unroll
  for (int e = 0; e < 9; ++e) {
    dr[e] = __shfl_up(sr[e], (unsigned)delta, 64);
    di[e] = __shfl_up(si[e], (unsigned)delta, 64);
  }
}
__device__ __forceinline__ void shdn(float* dr, float* di, const float* sr, const float* si, int delta) {
#pragma unroll
  for (int e = 0; e < 9; ++e) {
    dr[e] = __shfl_down(sr[e], (unsigned)delta, 64);
    di[e] = __shfl_down(si[e], (unsigned)delta, 64);
  }
}

__device__ __forceinline__ void ldm9(const float* __restrict__ L, float* v) {
#pragma unroll
  for (int e = 0; e < 9; ++e) v[e] = L[e];
}
__device__ __forceinline__ void stm9(float* __restrict__ L, const float* v) {
#pragma unroll
  for (int e = 0; e < 9; ++e) L[e] = v[e];
}

struct Tile { int mu, s00, st; };

__device__ __forceinline__ Tile tileGeom(int O) {
  Tile tg;
  int mu = O / OCT;
  int l0 = (O - mu * OCT) * LPB;
  int cC0 = l0 % LSIZE;
  int cB0 = (l0 / LSIZE) % LSIZE;
  int cA0 = l0 / (LSIZE * LSIZE);
  if (mu == 0)      { tg.s00 = l0;                          tg.st = 13824; }
  else if (mu == 1) { tg.s00 = cA0*13824 + cB0*24 + cC0;    tg.st = 576; }
  else if (mu == 2) { tg.s00 = cA0*13824 + cB0*576 + cC0;   tg.st = 24; }
  else              { tg.s00 = l0 * 24;                     tg.st = 1; }
  tg.mu = mu;
  return tg;
}

// global dword offset (within one re/im array) of image dword da
__device__ __forceinline__ int chunkAddr(int mu, int s00, int st, int da) {
  if (mu == 3) return s00 * 9 + da;
  int slab = da / 72;
  return (s00 + slab * st) * 9 + (da - slab * 72);
}

// One wave per block, NT tiles software-pipelined through 14 float4 staging
// registers. Single 13824B LDS image per tile (in-place output, R4 layout).
// Only tile 0 pays a vmcnt(0) drain; later tiles use counted vmcnt(14) so the
// previous tile's 14 stores stay in flight while its prefetch loads retire.
// Zero __syncthreads (wave-local lgkmcnt ordering only).
__global__ __launch_bounds__(TPB, 3) void polyakov_pipe(
    const float* __restrict__ U_re, const float* __restrict__ U_im,
    float* __restrict__ out) {
  __shared__ __align__(16) float lds[2 * IMG];   // 13824 B

  const int lane = threadIdx.x;
  float4 stg[14];                                // compile-time indexed only

  // ---- prologue: issue loads for tile 0 ----
  {
    Tile tg = tileGeom(blockIdx.x * NT);
    const float* __restrict__ gR = U_re + (size_t)tg.mu * (VOL*9);
    const float* __restrict__ gI = U_im + (size_t)tg.mu * (VOL*9);
#pragma unroll
    for (int p = 0; p < 14; ++p) {
      int c = p * 64 + lane;
      if (c < NCHUNK) {
        int d = c << 2;
        int arr = d >= IMG;
        int da = d - (arr ? IMG : 0);
        stg[p] = *(const float4*)((arr ? gI : gR) + chunkAddr(tg.mu, tg.s00, tg.st, da));
      }
    }
  }

#pragma unroll 1
  for (int t = 0; t < NT; ++t) {
    const Tile tg = tileGeom(blockIdx.x * NT + t);
    const int mu = tg.mu;

    // stg ready; prev tile's stage-out ds_reads done (buffer reusable)
    if (t == 0) { asm volatile("s_waitcnt vmcnt(0)" ::: "memory"); }
    else        { asm volatile("s_waitcnt vmcnt(14)" ::: "memory"); }
    asm volatile("s_waitcnt lgkmcnt(0)" ::: "memory");
    __builtin_amdgcn_sched_barrier(0);

    // materialize image in LDS
#pragma unroll
    for (int p = 0; p < 14; ++p) {
      int c = p * 64 + lane;
      if (c < NCHUNK) *(float4*)(&lds[c << 2]) = stg[p];
    }

    // issue next tile's loads now; latency hides under this tile's compute
    if (t + 1 < NT) {
      Tile tn = tileGeom(blockIdx.x * NT + t + 1);
      const float* __restrict__ gR = U_re + (size_t)tn.mu * (VOL*9);
      const float* __restrict__ gI = U_im + (size_t)tn.mu * (VOL*9);
#pragma unroll
      for (int p = 0; p < 14; ++p) {
        int c = p * 64 + lane;
        if (c < NCHUNK) {
          int d = c << 2;
          int arr = d >= IMG;
          int da = d - (arr ? IMG : 0);
          stg[p] = *(const float4*)((arr ? gI : gR) + chunkAddr(tn.mu, tn.s00, tn.st, da));
        }
      }
    }

    asm volatile("s_waitcnt lgkmcnt(0)" ::: "memory");   // image visible
    __builtin_amdgcn_sched_barrier(0);

    // ---------------- compute (R4 core, verbatim) ----------------
    const int tl = lane >> 3;
    const int ll = lane & 7;
    const int k0 = 3 * tl;
    const int uo = (mu == 3) ? ll * 216 : ll * 9;
    const int ks = (mu == 3) ? 9 : 72;
    float* mR = lds + uo;
    float* mI = lds + IMG + uo;

    float Br[9], Bi[9], Yr[9], Yi[9], Tr[9], Ti[9];
    {
      float Ar[9], Ai[9];
      ldm9(mR + (k0+0)*ks, Yr); ldm9(mI + (k0+0)*ks, Yi);   // U0
      ldm9(mR + (k0+1)*ks, Ar); ldm9(mI + (k0+1)*ks, Ai);   // U1
      cmul(Yr, Yi, Ar, Ai, Tr, Ti);                         // U0*U1
      ldm9(mR + (k0+2)*ks, Ar); ldm9(mI + (k0+2)*ks, Ai);   // U2
      cmul(Tr, Ti, Ar, Ai, Br, Bi);                         // B
    }

    // inclusive prefix scan -> exclusive end P = B_0..B_{t-1}
    float Pr[9], Pi[9];
    {
      float Xr[9], Xi[9];
      cp9(Xr, Xi, Br, Bi);
#pragma unroll
      for (int d = 1; d < 8; d <<= 1) {
        shup(Yr, Yi, Xr, Xi, 8 * d);
        if (tl >= d) { cmul(Yr, Yi, Xr, Xi, Tr, Ti); cp9(Xr, Xi, Tr, Ti); }
      }
      shup(Pr, Pi, Xr, Xi, 8);
      if (tl == 0) setid(Pr, Pi);
    }
    // inclusive suffix scan -> exclusive end Q = B_{t+1}..B_7 ; R = Q*P
    float Rr[9], Ri[9];
    {
      float Zr[9], Zi[9];
      cp9(Zr, Zi, Br, Bi);
#pragma unroll
      for (int d = 1; d < 8; d <<= 1) {
        shdn(Yr, Yi, Zr, Zi, 8 * d);
        if (tl + d < 8) { cmul(Zr, Zi, Yr, Yi, Tr, Ti); cp9(Zr, Zi, Tr, Ti); }
      }
      shdn(Yr, Yi, Zr, Zi, 8);
      if (tl == 7) setid(Yr, Yi);
      cmul(Yr, Yi, Pr, Pi, Rr, Ri);          // R
    }

    // outputs in-place (single-owner slots; reloads precede overwrites)
    ldm9(mR + (k0+0)*ks, Pr); ldm9(mI + (k0+0)*ks, Pi);     // U0
    cmul(Br, Bi, Rr, Ri, Tr, Ti);                           // out0 = B*R
    stm9(mR + (k0+0)*ks, Tr); stm9(mI + (k0+0)*ks, Ti);

    float W2r[9], W2i[9], U1r[9], U1i[9], W1r[9], W1i[9];
    ldm9(mR + (k0+2)*ks, Yr); ldm9(mI + (k0+2)*ks, Yi);     // U2
    cmul(Yr, Yi, Rr, Ri, W2r, W2i);                         // W2 = U2*R
    ldm9(mR + (k0+1)*ks, U1r); ldm9(mI + (k0+1)*ks, U1i);   // U1
    cmul(U1r, U1i, W2r, W2i, W1r, W1i);                     // W1 = U1*W2
    cmul(W1r, W1i, Pr, Pi, Tr, Ti);                         // out1 = W1*U0
    stm9(mR + (k0+1)*ks, Tr); stm9(mI + (k0+1)*ks, Ti);
    cmul(W2r, W2i, Pr, Pi, Yr, Yi);                         // V = W2*U0
    cmul(Yr, Yi, U1r, U1i, Tr, Ti);                         // out2 = V*U1
    stm9(mR + (k0+2)*ks, Tr); stm9(mI + (k0+2)*ks, Ti);

    asm volatile("s_waitcnt lgkmcnt(0)" ::: "memory");
    __builtin_amdgcn_sched_barrier(0);

    // ---------------- stage out (aligned 16B, stores left in flight) ----------------
    float* __restrict__ oR = out + (size_t)mu * (VOL*9);
    float* __restrict__ oI = out + (size_t)(4 + mu) * (VOL*9);
#pragma unroll
    for (int p = 0; p < 14; ++p) {
      int c = p * 64 + lane;
      if (c < NCHUNK) {
        int d = c << 2;
        int arr = d >= IMG;
        int da = d - (arr ? IMG : 0);
        float4 v = *(const float4*)(&lds[d]);
        *(float4*)((arr ? oI : oR) + chunkAddr(mu, tg.s00, tg.st, da)) = v;
      }
    }
  }
}

extern "C" void kernel_launch(void* const* d_in, const int* in_sizes, int n_in,
                              void* d_out, int out_size, void* d_ws, size_t ws_size,
                              hipStream_t stream) {
  const float* U_re = (const float*)d_in[0];
  const float* U_im = (const float*)d_in[1];
  float* out = (float*)d_out;
  int nblocks = 4 * OCT / NT;   // 3456 blocks x 64 threads
  hipLaunchKernelGGL(polyakov_pipe, dim3(nblocks), dim3(TPB), 0, stream, U_re, U_im, out);
}

// Round 7
// 203.664 us; speedup vs baseline: 1.3946x; 1.3946x over previous
//
#include <hip/hip_runtime.h>

#define LSIZE 24
#define VOL (LSIZE*LSIZE*LSIZE*LSIZE)       // 331776 sites
#define NLINES (LSIZE*LSIZE*LSIZE)          // 13824 lines per direction
#define LPB 8                               // lines per tile (= 1 wave)
#define TPB 64
#define NT 4                                // tiles per block, double-buffered LDS
#define OCT (NLINES/LPB)                    // 1728 octet-tiles per direction
#define IMG 1728                            // dwords per re/im half-image (8*24*9)
#define NCHUNK 864                          // float4 chunks per tile image

// (o_re,o_im) = a * b, complex 3x3 matmul (row-major). Output must not alias inputs.
__device__ __forceinline__ void cmul(const float* __restrict__ ar, const float* __restrict__ ai,
                                     const float* __restrict__ br, const float* __restrict__ bi,
                                     float* __restrict__ or_, float* __restrict__ oi_) {
#pragma unroll
  for (int i = 0; i < 3; ++i) {
#pragma unroll
    for (int j = 0; j < 3; ++j) {
      float sr = 0.f, si = 0.f;
#pragma unroll
      for (int m = 0; m < 3; ++m) {
        float x = ar[i*3+m], y = ai[i*3+m];
        float u = br[m*3+j], v = bi[m*3+j];
        sr = fmaf(x, u, sr);
        sr = fmaf(-y, v, sr);
        si = fmaf(x, v, si);
        si = fmaf(y, u, si);
      }
      or_[i*3+j] = sr;
      oi_[i*3+j] = si;
    }
  }
}

__device__ __forceinline__ void cp9(float* dr, float* di, const float* sr, const float* si) {
#pragma unroll
  for (int e = 0; e < 9; ++e) { dr[e] = sr[e]; di[e] = si[e]; }
}

__device__ __forceinline__ void setid(float* r, float* im) {
#pragma unroll
  for (int e = 0; e < 9; ++e) { r[e] = (e == 0 || e == 4 || e == 8) ? 1.f : 0.f; im[e] = 0.f; }
}

__device__ __forceinline__ void shup(float* dr, float* di, const float* sr, const float* si, int delta) {
#pragma unroll
  for (int e = 0; e < 9; ++e) {
    dr[e] = __shfl_up(sr[e], (unsigned)delta, 64);
    di[e] = __shfl_up(si[e], (unsigned)delta, 64);
  }
}
__device__ __forceinline__ void shdn(float* dr, float* di, const float* sr, const float* si, int delta) {
#pragma unroll
  for (int e = 0; e < 9; ++e) {
    dr[e] = __shfl_down(sr[e], (unsigned)delta, 64);
    di[e] = __shfl_down(si[e], (unsigned)delta, 64);
  }
}

__device__ __forceinline__ void ldm9(const float* __restrict__ L, float* v) {
#pragma unroll
  for (int e = 0; e < 9; ++e) v[e] = L[e];
}
__device__ __forceinline__ void stm9(float* __restrict__ L, const float* v) {
#pragma unroll
  for (int e = 0; e < 9; ++e) L[e] = v[e];
}

struct Tile { int mu, s00, st; };

__device__ __forceinline__ Tile tileGeom(int O) {
  Tile tg;
  int mu = O / OCT;
  int l0 = (O - mu * OCT) * LPB;
  int cC0 = l0 % LSIZE;
  int cB0 = (l0 / LSIZE) % LSIZE;
  int cA0 = l0 / (LSIZE * LSIZE);
  if (mu == 0)      { tg.s00 = l0;                          tg.st = 13824; }
  else if (mu == 1) { tg.s00 = cA0*13824 + cB0*24 + cC0;    tg.st = 576; }
  else if (mu == 2) { tg.s00 = cA0*13824 + cB0*576 + cC0;   tg.st = 24; }
  else              { tg.s00 = l0 * 24;                     tg.st = 1; }
  tg.mu = mu;
  return tg;
}

// global dword offset (within one re/im array) of image dword da
__device__ __forceinline__ int chunkAddr(int mu, int s00, int st, int da) {
  if (mu == 3) return s00 * 9 + da;
  int slab = da / 72;
  return (s00 + slab * st) * 9 + (da - slab * 72);
}

// 14 async global->LDS loads for one tile image (exactly 14 vm ops; no VGPR staging)
__device__ __forceinline__ void issueLoads(const float* __restrict__ U_re,
                                           const float* __restrict__ U_im,
                                           Tile tg, float* dst, int lane) {
  const float* __restrict__ gR = U_re + (size_t)tg.mu * (VOL*9);
  const float* __restrict__ gI = U_im + (size_t)tg.mu * (VOL*9);
#pragma unroll
  for (int p = 0; p < 14; ++p) {
    int c = p * 64 + lane;
    if (c < NCHUNK) {
      int d = c << 2;
      int arr = d >= IMG;
      int da = d - (arr ? IMG : 0);
      const float* src = (arr ? gI : gR) + chunkAddr(tg.mu, tg.s00, tg.st, da);
      __builtin_amdgcn_global_load_lds(
          (const __attribute__((address_space(1))) void*)(const void*)src,
          (__attribute__((address_space(3))) void*)(void*)(dst + p * 256),
          16, 0, 0);
    }
  }
}

// One wave per block, NT tiles, double-buffered LDS images (27648 B).
// Per tile: counted vmcnt(14) retires this tile's 14 DMA loads (in-order vmcnt;
// the 14 float4 stores of the previous tile may stay in flight), issue next
// tile's DMA into the other buffer, compute (U0-U2 live in registers, in-wave
// shuffle scans), in-place output into the image, coalesced 16B stage-out with
// stores left in flight. Zero __syncthreads; only tile 0 pays a full drain.
__global__ __launch_bounds__(TPB, 1) void polyakov_db(
    const float* __restrict__ U_re, const float* __restrict__ U_im,
    float* __restrict__ out) {
  __shared__ __align__(16) float lds[4 * IMG];   // 27648 B = two tile images

  const int lane = threadIdx.x;
  const int base = blockIdx.x * NT;

  // prologue: DMA tile 0 into buffer 0
  issueLoads(U_re, U_im, tileGeom(base), lds, lane);

#pragma unroll 1
  for (int t = 0; t < NT; ++t) {
    const Tile tg = tileGeom(base + t);
    const int mu = tg.mu;
    float* buf = lds + (t & 1) * (2 * IMG);

    // retire this tile's 14 loads; prev tile's 14 stores may remain in flight
    if (t == 0) { asm volatile("s_waitcnt vmcnt(0)" ::: "memory"); }
    else        { asm volatile("s_waitcnt vmcnt(14)" ::: "memory"); }
    __builtin_amdgcn_sched_barrier(0);

    // prefetch next tile into the other buffer (latency hides under compute)
    if (t + 1 < NT)
      issueLoads(U_re, U_im, tileGeom(base + t + 1), lds + ((t + 1) & 1) * (2 * IMG), lane);

    // ---------------- compute ----------------
    const int tl = lane >> 3;
    const int ll = lane & 7;
    const int k0 = 3 * tl;
    const int uo = (mu == 3) ? ll * 216 : ll * 9;
    const int ks = (mu == 3) ? 9 : 72;
    float* mR = buf + uo;
    float* mI = buf + IMG + uo;

    // load the 3 owned links once; keep live (LDS, not VGPR, caps occupancy)
    float U0r[9], U0i[9], U1r[9], U1i[9], U2r[9], U2i[9];
    ldm9(mR + (k0+0)*ks, U0r); ldm9(mI + (k0+0)*ks, U0i);
    ldm9(mR + (k0+1)*ks, U1r); ldm9(mI + (k0+1)*ks, U1i);
    ldm9(mR + (k0+2)*ks, U2r); ldm9(mI + (k0+2)*ks, U2i);

    float Br[9], Bi[9], Tr[9], Ti[9], Yr[9], Yi[9];
    cmul(U0r, U0i, U1r, U1i, Tr, Ti);          // U0*U1
    cmul(Tr, Ti, U2r, U2i, Br, Bi);            // B = U0*U1*U2

    // inclusive prefix scan -> exclusive end P = B_0..B_{t-1}
    float Pr[9], Pi[9];
    {
      float Xr[9], Xi[9];
      cp9(Xr, Xi, Br, Bi);
#pragma unroll
      for (int d = 1; d < 8; d <<= 1) {
        shup(Yr, Yi, Xr, Xi, 8 * d);
        if (tl >= d) { cmul(Yr, Yi, Xr, Xi, Tr, Ti); cp9(Xr, Xi, Tr, Ti); }
      }
      shup(Pr, Pi, Xr, Xi, 8);
      if (tl == 0) setid(Pr, Pi);
    }
    // inclusive suffix scan -> exclusive end Q = B_{t+1}..B_7 ; R = Q*P
    float Rr[9], Ri[9];
    {
      float Zr[9], Zi[9];
      cp9(Zr, Zi, Br, Bi);
#pragma unroll
      for (int d = 1; d < 8; d <<= 1) {
        shdn(Yr, Yi, Zr, Zi, 8 * d);
        if (tl + d < 8) { cmul(Zr, Zi, Yr, Yi, Tr, Ti); cp9(Zr, Zi, Tr, Ti); }
      }
      shdn(Yr, Yi, Zr, Zi, 8);
      if (tl == 7) setid(Yr, Yi);
      cmul(Yr, Yi, Pr, Pi, Rr, Ri);            // R
    }

    // outputs in-place (single-owner slots)
    cmul(Br, Bi, Rr, Ri, Tr, Ti);              // out0 = B*R
    stm9(mR + (k0+0)*ks, Tr); stm9(mI + (k0+0)*ks, Ti);

    float W2r[9], W2i[9], W1r[9], W1i[9];
    cmul(U2r, U2i, Rr, Ri, W2r, W2i);          // W2 = U2*R
    cmul(U1r, U1i, W2r, W2i, W1r, W1i);        // W1 = U1*W2
    cmul(W1r, W1i, U0r, U0i, Tr, Ti);          // out1 = W1*U0
    stm9(mR + (k0+1)*ks, Tr); stm9(mI + (k0+1)*ks, Ti);
    cmul(W2r, W2i, U0r, U0i, Yr, Yi);          // V = W2*U0
    cmul(Yr, Yi, U1r, U1i, Tr, Ti);            // out2 = V*U1
    stm9(mR + (k0+2)*ks, Tr); stm9(mI + (k0+2)*ks, Ti);

    asm volatile("s_waitcnt lgkmcnt(0)" ::: "memory");   // image writes visible (wave-local)
    __builtin_amdgcn_sched_barrier(0);

    // ---------------- stage out: exactly 14 aligned dwordx4 stores ----------------
    float* __restrict__ oR = out + (size_t)mu * (VOL*9);
    float* __restrict__ oI = out + (size_t)(4 + mu) * (VOL*9);
#pragma unroll
    for (int p = 0; p < 14; ++p) {
      int c = p * 64 + lane;
      if (c < NCHUNK) {
        int d = c << 2;
        int arr = d >= IMG;
        int da = d - (arr ? IMG : 0);
        float4 v = *(const float4*)(&buf[d]);
        *(float4*)((arr ? oI : oR) + chunkAddr(mu, tg.s00, tg.st, da)) = v;
      }
    }
  }
}

extern "C" void kernel_launch(void* const* d_in, const int* in_sizes, int n_in,
                              void* d_out, int out_size, void* d_ws, size_t ws_size,
                              hipStream_t stream) {
  const float* U_re = (const float*)d_in[0];
  const float* U_im = (const float*)d_in[1];
  float* out = (float*)d_out;
  int nblocks = 4 * OCT / NT;   // 1728 blocks x 64 threads
  hipLaunchKernelGGL(polyakov_db, dim3(nblocks), dim3(TPB), 0, stream, U_re, U_im, out);
}